// Round 14
// baseline (146.483 us; speedup 1.0000x reference)
//
#include <hip/hip_runtime.h>
#include <hip/hip_bf16.h>

// GCN layer: out = (D^-1/2 A D^-1/2 X) W^T + b
// Round 24 = R23 (138.9us verified best) + R21's pair-load wide-window
// gather, now at 8 waves. The two k_fused wins were verified separately in
// the same R20-context (8-wave: 61.5->45.2; pair-load: 61.5->54.5) and
// attack different terms (cross-wave concurrency vs per-row serial window
// count). Combined: 4 rows/wave x ~1 window (32-neighbor windows, lanes
// 0-31 even / 32-63 odd neighbors, dwordx2/lane, 2nd sub-batch under a
// uniform pre-fmac guard), ~18 waves/CU.
//   k_bin: R23 verbatim (binning only).
//   k_ell: R23 verbatim (ELL build + W/xs casts overlapped).
//   k_fused epilogue: R21-verified cross-half shfl + lo-lane uint2 write;
//   MFMA: R23-verified 8-wave assignment (2 row-groups x 4 col-strips).
//
// ws: gbin[196*32] 25KB | pairs[196*32*224 u32] 5.6MB | dis[nrows f32]
//     200KB | degc[N] 50KB | ell[nrows*64 u16] 6.42MB | xs 12.85MB |
//     wb 32KB  ~= 25.2 MB (< 26 MB proven)

typedef short v8s __attribute__((ext_vector_type(8)));
typedef float v4f __attribute__((ext_vector_type(4)));

#define ELLCAP 64     // deg ~ Poisson(16); P(deg>64) ~ 1e-19/node. Guarded.
#define NSHARD 32     // reservation shards per bin (depth ~391/32 ~= 12)
#define SUBCAP 224    // per (bin,shard) ~ Poisson(131); +8 sigma. Guarded.
#define ROWSTRIDE 136 // 128 bf16 + 8 pad shorts; 272 B rows (16B-aligned)
#define EPB 2048      // edges per binning block (8 per thread, R18-proven)

static __device__ __forceinline__ unsigned int f2bf(float f) {
    __hip_bfloat16 h = __float2bfloat16(f);  // RNE
    return (unsigned int)__builtin_bit_cast(unsigned short, h);
}

// k_bin: binning only. 2048 edges/block; LDS hist -> sharded reservation
// (overlapped with LDS local-offset pass) -> packed (localrow,col) scatter.
__global__ __launch_bounds__(256) void k_bin(
    const int* __restrict__ idx, int* __restrict__ gbin,
    unsigned int* __restrict__ pairs, int E, int nbins) {
    const int b = blockIdx.x;
    const int t = threadIdx.x;
    __shared__ int hist[256];
    __shared__ int hist2[256];
    __shared__ int base[256];
    hist[t] = 0;
    hist2[t] = 0;
    __syncthreads();

    int e0 = b * EPB + t * 8;
    int nv = E - e0;
    nv = nv > 8 ? 8 : (nv < 0 ? 0 : nv);
    int rows[8], cols[8];
    if (nv == 8) {
        int4 a0 = *(const int4*)&idx[e0];
        int4 a1 = *(const int4*)&idx[e0 + 4];
        int4 c0 = *(const int4*)&idx[E + e0];
        int4 c1 = *(const int4*)&idx[E + e0 + 4];
        rows[0] = a0.x; rows[1] = a0.y; rows[2] = a0.z; rows[3] = a0.w;
        rows[4] = a1.x; rows[5] = a1.y; rows[6] = a1.z; rows[7] = a1.w;
        cols[0] = c0.x; cols[1] = c0.y; cols[2] = c0.z; cols[3] = c0.w;
        cols[4] = c1.x; cols[5] = c1.y; cols[6] = c1.z; cols[7] = c1.w;
    } else {
        for (int k = 0; k < 8; ++k) {
            rows[k] = (k < nv) ? idx[e0 + k] : 0;
            cols[k] = (k < nv) ? idx[E + e0 + k] : 0;
        }
    }
#pragma unroll
    for (int k = 0; k < 8; ++k)
        if (k < nv) atomicAdd(&hist[rows[k] >> 8], 1);
    __syncthreads();
    const int shard = b & (NSHARD - 1);
    if (t < nbins)  // ~12-deep contention; returns while hist2 pass runs
        base[t] = atomicAdd(&gbin[t * NSHARD + shard], hist[t]);
    // overlap: per-edge local offsets via LDS while reservations in flight
    int loc[8];
#pragma unroll
    for (int k = 0; k < 8; ++k)
        loc[k] = (k < nv) ? atomicAdd(&hist2[rows[k] >> 8], 1) : 0;
    __syncthreads();
#pragma unroll
    for (int k = 0; k < 8; ++k) {
        if (k < nv) {
            int bin = rows[k] >> 8;
            int pos = base[bin] + loc[k];
            if (pos < SUBCAP)
                pairs[((size_t)bin * NSHARD + shard) * SUBCAP + pos] =
                    (unsigned)(((rows[k] & 255) << 16) | cols[k]);
        }
    }
}

// k_ell: mixed grid, 1024 thr.
//   blocks [0,nbins): ELL build: 32 groups x 32 lanes scan sub-regions,
//     LDS ELL, 32KB coalesced dump, dis/degc.
//   blocks [nbins,nbins+4): W cast. [nbins+4,...): xs cast (4096 dwords).
__global__ __launch_bounds__(1024) void k_ell(
    const unsigned int* __restrict__ pairs, const int* __restrict__ gbin,
    unsigned short* __restrict__ ell, unsigned char* __restrict__ degc,
    float* __restrict__ dis, const float4* __restrict__ w4,
    ushort4* __restrict__ wb4, const float2* __restrict__ x2,
    unsigned int* __restrict__ xs32, int N, int nbins) {
    const int t = threadIdx.x;
    int b = blockIdx.x;
    if (b >= nbins) {
        b -= nbins;
        if (b < 4) {  // W cast: 4 blocks x 1024 thr = 4096 float4s
            int i = b * 1024 + t;
            float4 v = w4[i];
            ushort4 o;
            o.x = (unsigned short)f2bf(v.x);
            o.y = (unsigned short)f2bf(v.y);
            o.z = (unsigned short)f2bf(v.z);
            o.w = (unsigned short)f2bf(v.w);
            wb4[i] = o;
            return;
        }
        b -= 4;
        // xs cast: 4096 dwords (64 rows) per block, unscaled bf16
        int base = b * 4096;
#pragma unroll
        for (int it = 0; it < 4; ++it) {
            int i = base + it * 1024 + t;
            int lr = i >> 6;  // global row
            unsigned ov = 0u;
            if (lr < N) {
                float2 v = x2[i];
                ov = f2bf(v.x) | (f2bf(v.y) << 16);
            }
            xs32[i] = ov;  // rows >= N (incl. pad row N) -> zeros
        }
        return;
    }

    __shared__ __align__(16) unsigned short lell[256 * ELLCAP];  // 32 KB
    __shared__ int cnt[256];
    const int bin = b;
    if (t < 256) cnt[t] = 0;
    __syncthreads();

    {
        const int g = t >> 5, l32 = t & 31;  // group g owns sub-region g
        int m = gbin[bin * NSHARD + g];
        m = m > SUBCAP ? SUBCAP : m;
        size_t pb = ((size_t)bin * NSHARD + g) * SUBCAP;
        for (int i = l32; i < m; i += 32) {
            unsigned pv = pairs[pb + i];
            int la = pv >> 16;
            int slot = atomicAdd(&cnt[la], 1);
            if (slot < ELLCAP)
                lell[la * ELLCAP + slot] = (unsigned short)(pv & 0xFFFF);
        }
    }
    __syncthreads();

    if (t < 256) {
        int r = bin * 256 + t;
        int d = cnt[t];
        if (r < N) {
            dis[r] = (d > 0) ? rsqrtf((float)d) : 0.f;
            degc[r] = (unsigned char)(d > ELLCAP ? ELLCAP : d);
        } else {
            dis[r] = 0.f;  // incl. pad row N
        }
    }

    // coalesced ELL dump: 32 KB = 8192 dwords into ell rows [bin*256,+256)
    {
        unsigned int* gell = (unsigned int*)(ell + (size_t)bin * 256 * ELLCAP);
        const unsigned int* sell = (const unsigned int*)lell;
        for (int i = t; i < 8192; i += 1024) gell[i] = sell[i];
    }
}

// k_fused: 512 thr (8 waves), 32 rows/block, 4 rows/wave. Pair-load gather:
// lanes 0-31 own even neighbors, 32-63 odd; dwordx2/lane (4 ch); 32-neighbor
// window = 2 guarded 8-load sub-batches issued before any fmac. Cross-half
// shfl combine; lo lanes write uint2. 8-wave MFMA epilogue (R23-verified).
__global__ __launch_bounds__(512) void k_fused(
    const unsigned short* __restrict__ ell, const unsigned char* __restrict__ degc,
    const float* __restrict__ dis, const unsigned int* __restrict__ xs32,
    const v8s* __restrict__ Wb8, const float* __restrict__ bias,
    float* __restrict__ out, int N) {
    __shared__ __align__(16) unsigned short smem[32 * ROWSTRIDE];
    const int nb0 = blockIdx.x * 32;
    const int wv = threadIdx.x >> 6, lane = threadIdx.x & 63;
    const int rowbase = nb0 + wv * 4;
    const bool lo = lane < 32;
    const int hl = lane & 31;

    // prologue: independent loads for all 4 rows (no serial chains)
    int d4[4], c4[4];
#pragma unroll
    for (int i = 0; i < 4; ++i) {
        int n = rowbase + i;
        int d = (n < N) ? degc[n] : 0;
        d4[i] = __builtin_amdgcn_readfirstlane(d);
        int cl = (n < N) ? ell[(size_t)n * ELLCAP + lane] : 0;
        c4[i] = (lane < d4[i]) ? cl : N;  // pad -> zero row, dis=0
    }
    float dv4[4];
#pragma unroll
    for (int i = 0; i < 4; ++i) dv4[i] = dis[c4[i]];  // 4 independent gathers

#pragma unroll
    for (int i = 0; i < 4; ++i) {
        float a0 = 0.f, a1 = 0.f, a2 = 0.f, a3 = 0.f;
        const int d = d4[i];
        const int c = c4[i];
        const int dcb = __builtin_bit_cast(int, dv4[i]);
        for (int j = 0; j < d; j += 32) {  // ~always exactly 1 iteration
            uint2 ua[8];
            float fa[8];
            // sub-batch A: neighbors j..j+15 (8 pair-loads)
#pragma unroll
            for (int k = 0; k < 8; ++k) {
                int ce = __builtin_amdgcn_readlane(c, j + 2 * k);
                int co = __builtin_amdgcn_readlane(c, j + 2 * k + 1);
                int se = __builtin_amdgcn_readlane(dcb, j + 2 * k);
                int so = __builtin_amdgcn_readlane(dcb, j + 2 * k + 1);
                int row = lo ? ce : co;
                fa[k] = __builtin_bit_cast(float, lo ? se : so);
                ua[k] = *(const uint2*)&xs32[(size_t)row * 64 + hl * 2];
            }
            uint2 ub[8];
            float fb[8];
            const bool doB = (j + 16) < d;  // uniform branch, BEFORE fmacs
            if (doB) {                      // sub-batch B: neighbors j+16..j+31
#pragma unroll
                for (int k = 0; k < 8; ++k) {
                    int ce = __builtin_amdgcn_readlane(c, j + 16 + 2 * k);
                    int co = __builtin_amdgcn_readlane(c, j + 17 + 2 * k);
                    int se = __builtin_amdgcn_readlane(dcb, j + 16 + 2 * k);
                    int so = __builtin_amdgcn_readlane(dcb, j + 17 + 2 * k);
                    int row = lo ? ce : co;
                    fb[k] = __builtin_bit_cast(float, lo ? se : so);
                    ub[k] = *(const uint2*)&xs32[(size_t)row * 64 + hl * 2];
                }
            }
            // fmacs A (one vmcnt drain covers both sub-batches)
#pragma unroll
            for (int k = 0; k < 8; ++k) {
                a0 = fmaf(fa[k], __builtin_bit_cast(float, ua[k].x << 16), a0);
                a1 = fmaf(fa[k],
                          __builtin_bit_cast(float, ua[k].x & 0xFFFF0000u), a1);
                a2 = fmaf(fa[k], __builtin_bit_cast(float, ua[k].y << 16), a2);
                a3 = fmaf(fa[k],
                          __builtin_bit_cast(float, ua[k].y & 0xFFFF0000u), a3);
            }
            if (doB) {
#pragma unroll
                for (int k = 0; k < 8; ++k) {
                    a0 = fmaf(fb[k], __builtin_bit_cast(float, ub[k].x << 16), a0);
                    a1 = fmaf(fb[k],
                              __builtin_bit_cast(float, ub[k].x & 0xFFFF0000u), a1);
                    a2 = fmaf(fb[k], __builtin_bit_cast(float, ub[k].y << 16), a2);
                    a3 = fmaf(fb[k],
                              __builtin_bit_cast(float, ub[k].y & 0xFFFF0000u), a3);
                }
            }
        }
        // cross-half combine: lanes 0-31 hold even-neighbor partials,
        // lanes 32-63 odd partials, same channels 4*hl..4*hl+3
        a0 += __shfl(a0, lane ^ 32, 64);
        a1 += __shfl(a1, lane ^ 32, 64);
        a2 += __shfl(a2, lane ^ 32, 64);
        a3 += __shfl(a3, lane ^ 32, 64);
        const int n = rowbase + i;
        float s = dis[n];  // rows >= N read dis=0 (sized nrows)
        a0 *= s; a1 *= s; a2 *= s; a3 *= s;
        if (lo) {  // lanes 0-31 write 4 channels (8B) each: full 128-ch row
            uint2 pk;
            pk.x = f2bf(a0) | (f2bf(a1) << 16);
            pk.y = f2bf(a2) | (f2bf(a3) << 16);
            *(uint2*)&smem[(size_t)(wv * 4 + i) * ROWSTRIDE + hl * 4] = pk;
        }
    }
    __syncthreads();

    // MFMA 8-wave epilogue (verified fragment math: A m=lane&15 k=quad*8+i;
    // B row-major W bf16; C/D col=lane&15 row=quad*4+reg). Group g=wv>>2
    // owns rows [g*16,g*16+16); wave-in-group w4 owns cols [w4*32,+32).
    {
        int g = wv >> 2, w4 = wv & 3;
        int quad = lane >> 4, m16 = lane & 15;
        int lrow = g * 16 + m16;
        v8s afrag[4];
#pragma unroll
        for (int kk = 0; kk < 4; ++kk)
            afrag[kk] = *(const v8s*)&smem[lrow * ROWSTRIDE + kk * 32 + quad * 8];
        int rbase = nb0 + g * 16 + quad * 4;
        int jbase = w4 * 32;
#pragma unroll
        for (int jt = 0; jt < 2; ++jt) {
            int jcol = jbase + jt * 16 + m16;
            v4f acc = {0.f, 0.f, 0.f, 0.f};
#pragma unroll
            for (int kk = 0; kk < 4; ++kk) {
                v8s bfrag = Wb8[jcol * 16 + kk * 4 + quad];
                acc = __builtin_amdgcn_mfma_f32_16x16x32_bf16(afrag[kk], bfrag,
                                                              acc, 0, 0, 0);
            }
            float bj = bias[jcol];
#pragma unroll
            for (int r = 0; r < 4; ++r) {
                int row = rbase + r;
                if (row < N) out[(size_t)row * 128 + jcol] = acc[r] + bj;
            }
        }
    }
}

extern "C" void kernel_launch(void* const* d_in, const int* in_sizes, int n_in,
                              void* d_out, int out_size, void* d_ws, size_t ws_size,
                              hipStream_t stream) {
    const float* x = (const float*)d_in[0];
    const int* idx = (const int*)d_in[1];
    const float* W = (const float*)d_in[2];
    const float* b = (const float*)d_in[3];
    float* out = (float*)d_out;

    const int N = in_sizes[0] / 128;    // 50000
    const int E = in_sizes[1] / 2;      // 800000
    const int nbins = (N + 255) / 256;  // 196 (<= 256 required)
    const int nrows = nbins * 256;      // 50176 (covers pad row N)
    const int ncast = nrows / 64;       // 784 xs-cast blocks x 4096 dwords

    char* p = (char*)d_ws;
    auto alloc = [&](size_t bytes) {
        char* r = p;
        p += (bytes + 63) & ~(size_t)63;
        return r;
    };
    int* gbin = (int*)alloc((size_t)nbins * NSHARD * 4);  // 25 KB
    unsigned int* pairs =
        (unsigned int*)alloc((size_t)nbins * NSHARD * SUBCAP * 4);  // 5.6 MB
    float* dis = (float*)alloc((size_t)nrows * 4);                  // 200 KB
    unsigned char* degc = (unsigned char*)alloc((size_t)N);         // 50 KB
    unsigned short* ell =
        (unsigned short*)alloc((size_t)nrows * ELLCAP * 2);  // 6.42 MB (nrows!)
    unsigned int* xs = (unsigned int*)alloc((size_t)nrows * 128 * 2);  // 12.85 MB
    ushort4* wb = (ushort4*)alloc(128 * 128 * 2);                      // 32 KB

    hipMemsetAsync(gbin, 0, (size_t)nbins * NSHARD * sizeof(int), stream);

    const int bblocks = (E + EPB - 1) / EPB;  // 391, binning only
    k_bin<<<bblocks, 256, 0, stream>>>(idx, gbin, pairs, E, nbins);
    // 196 ELL + 4 W-cast + 784 xs-cast blocks, casts overlap the pairs scan
    k_ell<<<nbins + 4 + ncast, 1024, 0, stream>>>(pairs, gbin, ell, degc, dis,
                                                  (const float4*)W, wb,
                                                  (const float2*)x, xs, N, nbins);
    k_fused<<<(N + 31) / 32, 512, 0, stream>>>(ell, degc, dis, xs,
                                               (const v8s*)wb, b, out, N);
}

// Round 15
// 144.302 us; speedup vs baseline: 1.0151x; 1.0151x over previous
//
#include <hip/hip_runtime.h>
#include <hip/hip_bf16.h>

// GCN layer: out = (D^-1/2 A D^-1/2 X) W^T + b
// Round 25 = R23 (138.9us verified best) with the k_fused gather rebuilt as
// dwordx4 row-split loads. R24 falsified pair-load+8wave stacking (VALU-
// per-edge binds at high wave count). This cut REMOVES instructions: lane
// group g=lane>>4 takes neighbor j+4k+g; each lane loads uint4 (16B =
// channels 8*(lane&15)..+7). One wave-load covers 4 neighbor rows: per 16
// neighbors 4 loads + 8 bpermutes (vs 16 loads + 32 readlanes). fmacs
// unchanged. Epilogue: xor-shuffle reduce across groups (lane^16, lane^32),
// lanes 0-15 write uint4 to the same verified smem layout; MFMA untouched.
//   k_bin: R23 verbatim (binning only).
//   k_ell: R23 verbatim (ELL build + W/xs casts overlapped).
//
// ws: gbin[196*32] 25KB | pairs[196*32*224 u32] 5.6MB | dis[nrows f32]
//     200KB | degc[N] 50KB | ell[nrows*64 u16] 6.42MB | xs 12.85MB |
//     wb 32KB  ~= 25.2 MB (< 26 MB proven)

typedef short v8s __attribute__((ext_vector_type(8)));
typedef float v4f __attribute__((ext_vector_type(4)));

#define ELLCAP 64     // deg ~ Poisson(16); P(deg>64) ~ 1e-19/node. Guarded.
#define NSHARD 32     // reservation shards per bin (depth ~391/32 ~= 12)
#define SUBCAP 224    // per (bin,shard) ~ Poisson(131); +8 sigma. Guarded.
#define ROWSTRIDE 136 // 128 bf16 + 8 pad shorts; 272 B rows (16B-aligned)
#define EPB 2048      // edges per binning block (8 per thread, R18-proven)

static __device__ __forceinline__ unsigned int f2bf(float f) {
    __hip_bfloat16 h = __float2bfloat16(f);  // RNE
    return (unsigned int)__builtin_bit_cast(unsigned short, h);
}

// k_bin: binning only. 2048 edges/block; LDS hist -> sharded reservation
// (overlapped with LDS local-offset pass) -> packed (localrow,col) scatter.
__global__ __launch_bounds__(256) void k_bin(
    const int* __restrict__ idx, int* __restrict__ gbin,
    unsigned int* __restrict__ pairs, int E, int nbins) {
    const int b = blockIdx.x;
    const int t = threadIdx.x;
    __shared__ int hist[256];
    __shared__ int hist2[256];
    __shared__ int base[256];
    hist[t] = 0;
    hist2[t] = 0;
    __syncthreads();

    int e0 = b * EPB + t * 8;
    int nv = E - e0;
    nv = nv > 8 ? 8 : (nv < 0 ? 0 : nv);
    int rows[8], cols[8];
    if (nv == 8) {
        int4 a0 = *(const int4*)&idx[e0];
        int4 a1 = *(const int4*)&idx[e0 + 4];
        int4 c0 = *(const int4*)&idx[E + e0];
        int4 c1 = *(const int4*)&idx[E + e0 + 4];
        rows[0] = a0.x; rows[1] = a0.y; rows[2] = a0.z; rows[3] = a0.w;
        rows[4] = a1.x; rows[5] = a1.y; rows[6] = a1.z; rows[7] = a1.w;
        cols[0] = c0.x; cols[1] = c0.y; cols[2] = c0.z; cols[3] = c0.w;
        cols[4] = c1.x; cols[5] = c1.y; cols[6] = c1.z; cols[7] = c1.w;
    } else {
        for (int k = 0; k < 8; ++k) {
            rows[k] = (k < nv) ? idx[e0 + k] : 0;
            cols[k] = (k < nv) ? idx[E + e0 + k] : 0;
        }
    }
#pragma unroll
    for (int k = 0; k < 8; ++k)
        if (k < nv) atomicAdd(&hist[rows[k] >> 8], 1);
    __syncthreads();
    const int shard = b & (NSHARD - 1);
    if (t < nbins)  // ~12-deep contention; returns while hist2 pass runs
        base[t] = atomicAdd(&gbin[t * NSHARD + shard], hist[t]);
    // overlap: per-edge local offsets via LDS while reservations in flight
    int loc[8];
#pragma unroll
    for (int k = 0; k < 8; ++k)
        loc[k] = (k < nv) ? atomicAdd(&hist2[rows[k] >> 8], 1) : 0;
    __syncthreads();
#pragma unroll
    for (int k = 0; k < 8; ++k) {
        if (k < nv) {
            int bin = rows[k] >> 8;
            int pos = base[bin] + loc[k];
            if (pos < SUBCAP)
                pairs[((size_t)bin * NSHARD + shard) * SUBCAP + pos] =
                    (unsigned)(((rows[k] & 255) << 16) | cols[k]);
        }
    }
}

// k_ell: mixed grid, 1024 thr.
//   blocks [0,nbins): ELL build: 32 groups x 32 lanes scan sub-regions,
//     LDS ELL, 32KB coalesced dump, dis/degc.
//   blocks [nbins,nbins+4): W cast. [nbins+4,...): xs cast (4096 dwords).
__global__ __launch_bounds__(1024) void k_ell(
    const unsigned int* __restrict__ pairs, const int* __restrict__ gbin,
    unsigned short* __restrict__ ell, unsigned char* __restrict__ degc,
    float* __restrict__ dis, const float4* __restrict__ w4,
    ushort4* __restrict__ wb4, const float2* __restrict__ x2,
    unsigned int* __restrict__ xs32, int N, int nbins) {
    const int t = threadIdx.x;
    int b = blockIdx.x;
    if (b >= nbins) {
        b -= nbins;
        if (b < 4) {  // W cast: 4 blocks x 1024 thr = 4096 float4s
            int i = b * 1024 + t;
            float4 v = w4[i];
            ushort4 o;
            o.x = (unsigned short)f2bf(v.x);
            o.y = (unsigned short)f2bf(v.y);
            o.z = (unsigned short)f2bf(v.z);
            o.w = (unsigned short)f2bf(v.w);
            wb4[i] = o;
            return;
        }
        b -= 4;
        // xs cast: 4096 dwords (64 rows) per block, unscaled bf16
        int base = b * 4096;
#pragma unroll
        for (int it = 0; it < 4; ++it) {
            int i = base + it * 1024 + t;
            int lr = i >> 6;  // global row
            unsigned ov = 0u;
            if (lr < N) {
                float2 v = x2[i];
                ov = f2bf(v.x) | (f2bf(v.y) << 16);
            }
            xs32[i] = ov;  // rows >= N (incl. pad row N) -> zeros
        }
        return;
    }

    __shared__ __align__(16) unsigned short lell[256 * ELLCAP];  // 32 KB
    __shared__ int cnt[256];
    const int bin = b;
    if (t < 256) cnt[t] = 0;
    __syncthreads();

    {
        const int g = t >> 5, l32 = t & 31;  // group g owns sub-region g
        int m = gbin[bin * NSHARD + g];
        m = m > SUBCAP ? SUBCAP : m;
        size_t pb = ((size_t)bin * NSHARD + g) * SUBCAP;
        for (int i = l32; i < m; i += 32) {
            unsigned pv = pairs[pb + i];
            int la = pv >> 16;
            int slot = atomicAdd(&cnt[la], 1);
            if (slot < ELLCAP)
                lell[la * ELLCAP + slot] = (unsigned short)(pv & 0xFFFF);
        }
    }
    __syncthreads();

    if (t < 256) {
        int r = bin * 256 + t;
        int d = cnt[t];
        if (r < N) {
            dis[r] = (d > 0) ? rsqrtf((float)d) : 0.f;
            degc[r] = (unsigned char)(d > ELLCAP ? ELLCAP : d);
        } else {
            dis[r] = 0.f;  // incl. pad row N
        }
    }

    // coalesced ELL dump: 32 KB = 8192 dwords into ell rows [bin*256,+256)
    {
        unsigned int* gell = (unsigned int*)(ell + (size_t)bin * 256 * ELLCAP);
        const unsigned int* sell = (const unsigned int*)lell;
        for (int i = t; i < 8192; i += 1024) gell[i] = sell[i];
    }
}

// k_fused: 512 thr (8 waves), 32 rows/block, 4 rows/wave. dwordx4 row-split
// gather: group g=lane>>4 takes neighbor j+4k+g; lane loads uint4 = channels
// 8*(lane&15)..+7 of that row. 16 neighbors = 4 loads + 8 bpermutes. Xor-
// shuffle group reduce; lanes 0-15 write uint4. 8-wave MFMA (R23-verified).
__global__ __launch_bounds__(512) void k_fused(
    const unsigned short* __restrict__ ell, const unsigned char* __restrict__ degc,
    const float* __restrict__ dis, const unsigned int* __restrict__ xs32,
    const v8s* __restrict__ Wb8, const float* __restrict__ bias,
    float* __restrict__ out, int N) {
    __shared__ __align__(16) unsigned short smem[32 * ROWSTRIDE];
    const int nb0 = blockIdx.x * 32;
    const int wv = threadIdx.x >> 6, lane = threadIdx.x & 63;
    const int rowbase = nb0 + wv * 4;
    const int grp = lane >> 4;   // neighbor sub-slot within each 4-group
    const int hl16 = lane & 15;  // channel-quad owner within the row
    const uint4* xs4 = (const uint4*)xs32;

    // prologue: independent loads for all 4 rows (no serial chains)
    int d4[4], c4[4];
    float dv4[4];
#pragma unroll
    for (int i = 0; i < 4; ++i) {
        int n = rowbase + i;
        int d = (n < N) ? degc[n] : 0;
        d4[i] = __builtin_amdgcn_readfirstlane(d);
        int cl = (n < N) ? ell[(size_t)n * ELLCAP + lane] : 0;
        c4[i] = (lane < d4[i]) ? cl : N;  // pad -> zero row, dis=0
    }
#pragma unroll
    for (int i = 0; i < 4; ++i) dv4[i] = dis[c4[i]];  // 4 independent gathers

#pragma unroll
    for (int i = 0; i < 4; ++i) {
        const int d = d4[i];
        const int c = c4[i];
        const int dvb = __builtin_bit_cast(int, dv4[i]);
        float acc[8] = {0.f, 0.f, 0.f, 0.f, 0.f, 0.f, 0.f, 0.f};
        for (int j = 0; j < d; j += 16) {  // 16 neighbors: 4 loads in flight
            uint4 uu[4];
            float sc[4];
#pragma unroll
            for (int k = 0; k < 4; ++k) {
                int idx = j + 4 * k + grp;  // < 64 always (d <= 64)
                int cm = __shfl(c, idx, 64);
                sc[k] = __builtin_bit_cast(float, __shfl(dvb, idx, 64));
                uu[k] = xs4[(size_t)cm * 16 + hl16];  // 16B of neighbor row
            }
#pragma unroll
            for (int k = 0; k < 4; ++k) {
                acc[0] = fmaf(sc[k], __builtin_bit_cast(float, uu[k].x << 16), acc[0]);
                acc[1] = fmaf(sc[k], __builtin_bit_cast(float, uu[k].x & 0xFFFF0000u), acc[1]);
                acc[2] = fmaf(sc[k], __builtin_bit_cast(float, uu[k].y << 16), acc[2]);
                acc[3] = fmaf(sc[k], __builtin_bit_cast(float, uu[k].y & 0xFFFF0000u), acc[3]);
                acc[4] = fmaf(sc[k], __builtin_bit_cast(float, uu[k].z << 16), acc[4]);
                acc[5] = fmaf(sc[k], __builtin_bit_cast(float, uu[k].z & 0xFFFF0000u), acc[5]);
                acc[6] = fmaf(sc[k], __builtin_bit_cast(float, uu[k].w << 16), acc[6]);
                acc[7] = fmaf(sc[k], __builtin_bit_cast(float, uu[k].w & 0xFFFF0000u), acc[7]);
            }
        }
        // reduce across the 4 neighbor groups (lanes l, l^16, l^32, l^48)
#pragma unroll
        for (int q = 0; q < 8; ++q) {
            acc[q] += __shfl(acc[q], lane ^ 16, 64);
            acc[q] += __shfl(acc[q], lane ^ 32, 64);
        }
        const int n = rowbase + i;
        float s = dis[n];  // rows >= N read dis=0 (sized nrows)
        if (lane < 16) {   // lane hl16 writes channels 8*hl16..+7 (16B)
            uint4 pk;
            pk.x = f2bf(acc[0] * s) | (f2bf(acc[1] * s) << 16);
            pk.y = f2bf(acc[2] * s) | (f2bf(acc[3] * s) << 16);
            pk.z = f2bf(acc[4] * s) | (f2bf(acc[5] * s) << 16);
            pk.w = f2bf(acc[6] * s) | (f2bf(acc[7] * s) << 16);
            *(uint4*)&smem[(size_t)(wv * 4 + i) * ROWSTRIDE + hl16 * 8] = pk;
        }
    }
    __syncthreads();

    // MFMA 8-wave epilogue (verified fragment math: A m=lane&15 k=quad*8+i;
    // B row-major W bf16; C/D col=lane&15 row=quad*4+reg). Group g=wv>>2
    // owns rows [g*16,g*16+16); wave-in-group w4 owns cols [w4*32,+32).
    {
        int g = wv >> 2, w4 = wv & 3;
        int quad = lane >> 4, m16 = lane & 15;
        int lrow = g * 16 + m16;
        v8s afrag[4];
#pragma unroll
        for (int kk = 0; kk < 4; ++kk)
            afrag[kk] = *(const v8s*)&smem[lrow * ROWSTRIDE + kk * 32 + quad * 8];
        int rbase = nb0 + g * 16 + quad * 4;
        int jbase = w4 * 32;
#pragma unroll
        for (int jt = 0; jt < 2; ++jt) {
            int jcol = jbase + jt * 16 + m16;
            v4f acc = {0.f, 0.f, 0.f, 0.f};
#pragma unroll
            for (int kk = 0; kk < 4; ++kk) {
                v8s bfrag = Wb8[jcol * 16 + kk * 4 + quad];
                acc = __builtin_amdgcn_mfma_f32_16x16x32_bf16(afrag[kk], bfrag,
                                                              acc, 0, 0, 0);
            }
            float bj = bias[jcol];
#pragma unroll
            for (int r = 0; r < 4; ++r) {
                int row = rbase + r;
                if (row < N) out[(size_t)row * 128 + jcol] = acc[r] + bj;
            }
        }
    }
}

extern "C" void kernel_launch(void* const* d_in, const int* in_sizes, int n_in,
                              void* d_out, int out_size, void* d_ws, size_t ws_size,
                              hipStream_t stream) {
    const float* x = (const float*)d_in[0];
    const int* idx = (const int*)d_in[1];
    const float* W = (const float*)d_in[2];
    const float* b = (const float*)d_in[3];
    float* out = (float*)d_out;

    const int N = in_sizes[0] / 128;    // 50000
    const int E = in_sizes[1] / 2;      // 800000
    const int nbins = (N + 255) / 256;  // 196 (<= 256 required)
    const int nrows = nbins * 256;      // 50176 (covers pad row N)
    const int ncast = nrows / 64;       // 784 xs-cast blocks x 4096 dwords

    char* p = (char*)d_ws;
    auto alloc = [&](size_t bytes) {
        char* r = p;
        p += (bytes + 63) & ~(size_t)63;
        return r;
    };
    int* gbin = (int*)alloc((size_t)nbins * NSHARD * 4);  // 25 KB
    unsigned int* pairs =
        (unsigned int*)alloc((size_t)nbins * NSHARD * SUBCAP * 4);  // 5.6 MB
    float* dis = (float*)alloc((size_t)nrows * 4);                  // 200 KB
    unsigned char* degc = (unsigned char*)alloc((size_t)N);         // 50 KB
    unsigned short* ell =
        (unsigned short*)alloc((size_t)nrows * ELLCAP * 2);  // 6.42 MB (nrows!)
    unsigned int* xs = (unsigned int*)alloc((size_t)nrows * 128 * 2);  // 12.85 MB
    ushort4* wb = (ushort4*)alloc(128 * 128 * 2);                      // 32 KB

    hipMemsetAsync(gbin, 0, (size_t)nbins * NSHARD * sizeof(int), stream);

    const int bblocks = (E + EPB - 1) / EPB;  // 391, binning only
    k_bin<<<bblocks, 256, 0, stream>>>(idx, gbin, pairs, E, nbins);
    // 196 ELL + 4 W-cast + 784 xs-cast blocks, casts overlap the pairs scan
    k_ell<<<nbins + 4 + ncast, 1024, 0, stream>>>(pairs, gbin, ell, degc, dis,
                                                  (const float4*)W, wb,
                                                  (const float2*)x, xs, N, nbins);
    k_fused<<<(N + 31) / 32, 512, 0, stream>>>(ell, degc, dis, xs,
                                               (const v8s*)wb, b, out, N);
}

// Round 16
// 138.452 us; speedup vs baseline: 1.0580x; 1.0423x over previous
//
#include <hip/hip_runtime.h>
#include <hip/hip_bf16.h>

// GCN layer: out = (D^-1/2 A D^-1/2 X) W^T + b
// Round 26 = R23 k_fused (verified 45.2us floor: 16-load windows, 8 waves;
// R25 proved the gather is outstanding-request-bound -- fewer/wider loads
// REDUCED MLP and regressed) + k_bin counting-sort coalesced scatter:
//   k_bin: hist -> Hillis-Steele exclusive scan -> LDS reorder (sorted by
//     bin) -> position-major write-out so consecutive lanes write
//     consecutive pairs addresses (~10-dword runs vs 800K scattered 4B
//     writes ~ 25MB effective). Reservation atomics issue before the
//     rank/reorder passes (round-trip hidden under LDS work).
//   k_ell: R23 verbatim (ELL build + W/xs casts overlapped).
//
// ws: gbin[196*32] 25KB | pairs[196*32*224 u32] 5.6MB | dis[nrows f32]
//     200KB | degc[N] 50KB | ell[nrows*64 u16] 6.42MB | xs 12.85MB |
//     wb 32KB  ~= 25.2 MB (< 26 MB proven)

typedef short v8s __attribute__((ext_vector_type(8)));
typedef float v4f __attribute__((ext_vector_type(4)));

#define ELLCAP 64     // deg ~ Poisson(16); P(deg>64) ~ 1e-19/node. Guarded.
#define NSHARD 32     // reservation shards per bin (depth ~391/32 ~= 12)
#define SUBCAP 224    // per (bin,shard) ~ Poisson(131); +8 sigma. Guarded.
#define ROWSTRIDE 136 // 128 bf16 + 8 pad shorts; 272 B rows (16B-aligned)
#define EPB 2048      // edges per binning block (8 per thread, R18-proven)

static __device__ __forceinline__ unsigned int f2bf(float f) {
    __hip_bfloat16 h = __float2bfloat16(f);  // RNE
    return (unsigned int)__builtin_bit_cast(unsigned short, h);
}

// k_bin: binning with block-local counting sort for coalesced pairs writes.
__global__ __launch_bounds__(256) void k_bin(
    const int* __restrict__ idx, int* __restrict__ gbin,
    unsigned int* __restrict__ pairs, int E, int nbins) {
    const int b = blockIdx.x;
    const int t = threadIdx.x;
    __shared__ int hist[256];
    __shared__ int sa[256], sb[256];     // scan ping-pong
    __shared__ int scanb[256];           // block-local exclusive prefix
    __shared__ int rank2[256];           // second-pass rank counters
    __shared__ int gbase[256];           // global reservation bases
    __shared__ unsigned lbuf[2048];      // bin-sorted packed pairs
    __shared__ unsigned char pbin[2048]; // bin of each sorted position
    hist[t] = 0;
    rank2[t] = 0;
    __syncthreads();

    int e0 = b * EPB + t * 8;
    int nv = E - e0;
    nv = nv > 8 ? 8 : (nv < 0 ? 0 : nv);
    int rows[8], cols[8];
    if (nv == 8) {
        int4 a0 = *(const int4*)&idx[e0];
        int4 a1 = *(const int4*)&idx[e0 + 4];
        int4 c0 = *(const int4*)&idx[E + e0];
        int4 c1 = *(const int4*)&idx[E + e0 + 4];
        rows[0] = a0.x; rows[1] = a0.y; rows[2] = a0.z; rows[3] = a0.w;
        rows[4] = a1.x; rows[5] = a1.y; rows[6] = a1.z; rows[7] = a1.w;
        cols[0] = c0.x; cols[1] = c0.y; cols[2] = c0.z; cols[3] = c0.w;
        cols[4] = c1.x; cols[5] = c1.y; cols[6] = c1.z; cols[7] = c1.w;
    } else {
        for (int k = 0; k < 8; ++k) {
            rows[k] = (k < nv) ? idx[e0 + k] : 0;
            cols[k] = (k < nv) ? idx[E + e0 + k] : 0;
        }
    }
#pragma unroll
    for (int k = 0; k < 8; ++k)
        if (k < nv) atomicAdd(&hist[rows[k] >> 8], 1);
    __syncthreads();

    const int shard = b & (NSHARD - 1);
    if (t < nbins)  // issue reservations now; round-trip hides under scan
        gbase[t] = atomicAdd(&gbin[t * NSHARD + shard], hist[t]);

    // Hillis-Steele inclusive scan over 256 entries (8 steps, ping-pong)
    sa[t] = hist[t];
    __syncthreads();
    int* src = sa;
    int* dst = sb;
#pragma unroll
    for (int off = 1; off < 256; off <<= 1) {
        int v = src[t];
        if (t >= off) v += src[t - off];
        dst[t] = v;
        __syncthreads();
        int* tmp = src; src = dst; dst = tmp;
    }
    scanb[t] = src[t] - hist[t];  // exclusive prefix
    __syncthreads();

    // rank + reorder into LDS sorted by bin
#pragma unroll
    for (int k = 0; k < 8; ++k) {
        if (k < nv) {
            int bin = rows[k] >> 8;
            int pos = scanb[bin] + atomicAdd(&rank2[bin], 1);
            lbuf[pos] = (unsigned)(((rows[k] & 255) << 16) | cols[k]);
            pbin[pos] = (unsigned char)bin;
        }
    }
    __syncthreads();

    // position-major write-out: consecutive lanes -> consecutive addresses
    const int total = src[255];  // valid edges in this block
#pragma unroll
    for (int q = 0; q < 8; ++q) {
        int pos = t + q * 256;
        if (pos < total) {
            int bin = pbin[pos];
            int dsti = gbase[bin] + (pos - scanb[bin]);
            if (dsti < SUBCAP)
                pairs[((size_t)bin * NSHARD + shard) * SUBCAP + dsti] = lbuf[pos];
        }
    }
}

// k_ell: mixed grid, 1024 thr.
//   blocks [0,nbins): ELL build: 32 groups x 32 lanes scan sub-regions,
//     LDS ELL, 32KB coalesced dump, dis/degc.
//   blocks [nbins,nbins+4): W cast. [nbins+4,...): xs cast (4096 dwords).
__global__ __launch_bounds__(1024) void k_ell(
    const unsigned int* __restrict__ pairs, const int* __restrict__ gbin,
    unsigned short* __restrict__ ell, unsigned char* __restrict__ degc,
    float* __restrict__ dis, const float4* __restrict__ w4,
    ushort4* __restrict__ wb4, const float2* __restrict__ x2,
    unsigned int* __restrict__ xs32, int N, int nbins) {
    const int t = threadIdx.x;
    int b = blockIdx.x;
    if (b >= nbins) {
        b -= nbins;
        if (b < 4) {  // W cast: 4 blocks x 1024 thr = 4096 float4s
            int i = b * 1024 + t;
            float4 v = w4[i];
            ushort4 o;
            o.x = (unsigned short)f2bf(v.x);
            o.y = (unsigned short)f2bf(v.y);
            o.z = (unsigned short)f2bf(v.z);
            o.w = (unsigned short)f2bf(v.w);
            wb4[i] = o;
            return;
        }
        b -= 4;
        // xs cast: 4096 dwords (64 rows) per block, unscaled bf16
        int base = b * 4096;
#pragma unroll
        for (int it = 0; it < 4; ++it) {
            int i = base + it * 1024 + t;
            int lr = i >> 6;  // global row
            unsigned ov = 0u;
            if (lr < N) {
                float2 v = x2[i];
                ov = f2bf(v.x) | (f2bf(v.y) << 16);
            }
            xs32[i] = ov;  // rows >= N (incl. pad row N) -> zeros
        }
        return;
    }

    __shared__ __align__(16) unsigned short lell[256 * ELLCAP];  // 32 KB
    __shared__ int cnt[256];
    const int bin = b;
    if (t < 256) cnt[t] = 0;
    __syncthreads();

    {
        const int g = t >> 5, l32 = t & 31;  // group g owns sub-region g
        int m = gbin[bin * NSHARD + g];
        m = m > SUBCAP ? SUBCAP : m;
        size_t pb = ((size_t)bin * NSHARD + g) * SUBCAP;
        for (int i = l32; i < m; i += 32) {
            unsigned pv = pairs[pb + i];
            int la = pv >> 16;
            int slot = atomicAdd(&cnt[la], 1);
            if (slot < ELLCAP)
                lell[la * ELLCAP + slot] = (unsigned short)(pv & 0xFFFF);
        }
    }
    __syncthreads();

    if (t < 256) {
        int r = bin * 256 + t;
        int d = cnt[t];
        if (r < N) {
            dis[r] = (d > 0) ? rsqrtf((float)d) : 0.f;
            degc[r] = (unsigned char)(d > ELLCAP ? ELLCAP : d);
        } else {
            dis[r] = 0.f;  // incl. pad row N
        }
    }

    // coalesced ELL dump: 32 KB = 8192 dwords into ell rows [bin*256,+256)
    {
        unsigned int* gell = (unsigned int*)(ell + (size_t)bin * 256 * ELLCAP);
        const unsigned int* sell = (const unsigned int*)lell;
        for (int i = t; i < 8192; i += 1024) gell[i] = sell[i];
    }
}

// k_fused (R23 VERBATIM, verified 45.2us): 512 thr (8 waves), 32 rows/block,
// 4 rows/wave. Prologue prefetch, 16-wide readlane batches, 8-wave MFMA.
__global__ __launch_bounds__(512) void k_fused(
    const unsigned short* __restrict__ ell, const unsigned char* __restrict__ degc,
    const float* __restrict__ dis, const unsigned int* __restrict__ xs32,
    const v8s* __restrict__ Wb8, const float* __restrict__ bias,
    float* __restrict__ out, int N) {
    __shared__ __align__(16) unsigned short smem[32 * ROWSTRIDE];
    const int nb0 = blockIdx.x * 32;
    const int wv = threadIdx.x >> 6, lane = threadIdx.x & 63;
    const int rowbase = nb0 + wv * 4;

    // prologue: independent loads for all 4 rows (no serial chains)
    int d4[4], c4[4];
    float dv4[4];
#pragma unroll
    for (int i = 0; i < 4; ++i) {
        int n = rowbase + i;
        int d = (n < N) ? degc[n] : 0;
        d4[i] = __builtin_amdgcn_readfirstlane(d);
        int cl = (n < N) ? ell[(size_t)n * ELLCAP + lane] : 0;
        c4[i] = (lane < d4[i]) ? cl : N;  // pad -> zero row, dis=0
    }
#pragma unroll
    for (int i = 0; i < 4; ++i) dv4[i] = dis[c4[i]];  // 4 independent gathers

#pragma unroll
    for (int i = 0; i < 4; ++i) {
        int n = rowbase + i;
        float acc0 = 0.f, acc1 = 0.f;
        int d = d4[i];
        int c = c4[i];
        int dcb = __builtin_bit_cast(int, dv4[i]);
        for (int j = 0; j < d; j += 16) {  // j in {0,16,32,48}
            int cc[16];
#pragma unroll
            for (int u = 0; u < 16; ++u)
                cc[u] = __builtin_amdgcn_readlane(c, j + u);
            unsigned uu[16];
#pragma unroll
            for (int u = 0; u < 16; ++u)
                uu[u] = xs32[(size_t)cc[u] * 64 + lane];
            float sc[16];
#pragma unroll
            for (int u = 0; u < 16; ++u)
                sc[u] = __builtin_bit_cast(float,
                                           __builtin_amdgcn_readlane(dcb, j + u));
#pragma unroll
            for (int u = 0; u < 16; ++u) {
                acc0 = fmaf(sc[u], __builtin_bit_cast(float, uu[u] << 16), acc0);
                acc1 = fmaf(sc[u],
                            __builtin_bit_cast(float, uu[u] & 0xFFFF0000u), acc1);
            }
        }
        float s = dis[n];  // rows >= N read dis=0 (sized nrows)
        acc0 *= s;
        acc1 *= s;
        unsigned pack = f2bf(acc0) | (f2bf(acc1) << 16);
        *(unsigned int*)&smem[(size_t)(wv * 4 + i) * ROWSTRIDE + lane * 2] = pack;
    }
    __syncthreads();

    // MFMA 8-wave epilogue (verified fragment math: A m=lane&15 k=quad*8+i;
    // B row-major W bf16; C/D col=lane&15 row=quad*4+reg). Group g=wv>>2
    // owns rows [g*16,g*16+16); wave-in-group w4 owns cols [w4*32,+32).
    {
        int g = wv >> 2, w4 = wv & 3;
        int quad = lane >> 4, m16 = lane & 15;
        int lrow = g * 16 + m16;
        v8s afrag[4];
#pragma unroll
        for (int kk = 0; kk < 4; ++kk)
            afrag[kk] = *(const v8s*)&smem[lrow * ROWSTRIDE + kk * 32 + quad * 8];
        int rbase = nb0 + g * 16 + quad * 4;
        int jbase = w4 * 32;
#pragma unroll
        for (int jt = 0; jt < 2; ++jt) {
            int jcol = jbase + jt * 16 + m16;
            v4f acc = {0.f, 0.f, 0.f, 0.f};
#pragma unroll
            for (int kk = 0; kk < 4; ++kk) {
                v8s bfrag = Wb8[jcol * 16 + kk * 4 + quad];
                acc = __builtin_amdgcn_mfma_f32_16x16x32_bf16(afrag[kk], bfrag,
                                                              acc, 0, 0, 0);
            }
            float bj = bias[jcol];
#pragma unroll
            for (int r = 0; r < 4; ++r) {
                int row = rbase + r;
                if (row < N) out[(size_t)row * 128 + jcol] = acc[r] + bj;
            }
        }
    }
}

extern "C" void kernel_launch(void* const* d_in, const int* in_sizes, int n_in,
                              void* d_out, int out_size, void* d_ws, size_t ws_size,
                              hipStream_t stream) {
    const float* x = (const float*)d_in[0];
    const int* idx = (const int*)d_in[1];
    const float* W = (const float*)d_in[2];
    const float* b = (const float*)d_in[3];
    float* out = (float*)d_out;

    const int N = in_sizes[0] / 128;    // 50000
    const int E = in_sizes[1] / 2;      // 800000
    const int nbins = (N + 255) / 256;  // 196 (<= 256 required)
    const int nrows = nbins * 256;      // 50176 (covers pad row N)
    const int ncast = nrows / 64;       // 784 xs-cast blocks x 4096 dwords

    char* p = (char*)d_ws;
    auto alloc = [&](size_t bytes) {
        char* r = p;
        p += (bytes + 63) & ~(size_t)63;
        return r;
    };
    int* gbin = (int*)alloc((size_t)nbins * NSHARD * 4);  // 25 KB
    unsigned int* pairs =
        (unsigned int*)alloc((size_t)nbins * NSHARD * SUBCAP * 4);  // 5.6 MB
    float* dis = (float*)alloc((size_t)nrows * 4);                  // 200 KB
    unsigned char* degc = (unsigned char*)alloc((size_t)N);         // 50 KB
    unsigned short* ell =
        (unsigned short*)alloc((size_t)nrows * ELLCAP * 2);  // 6.42 MB (nrows!)
    unsigned int* xs = (unsigned int*)alloc((size_t)nrows * 128 * 2);  // 12.85 MB
    ushort4* wb = (ushort4*)alloc(128 * 128 * 2);                      // 32 KB

    hipMemsetAsync(gbin, 0, (size_t)nbins * NSHARD * sizeof(int), stream);

    const int bblocks = (E + EPB - 1) / EPB;  // 391, binning only
    k_bin<<<bblocks, 256, 0, stream>>>(idx, gbin, pairs, E, nbins);
    // 196 ELL + 4 W-cast + 784 xs-cast blocks, casts overlap the pairs scan
    k_ell<<<nbins + 4 + ncast, 1024, 0, stream>>>(pairs, gbin, ell, degc, dis,
                                                  (const float4*)W, wb,
                                                  (const float2*)x, xs, N, nbins);
    k_fused<<<(N + 31) / 32, 512, 0, stream>>>(ell, degc, dis, xs,
                                               (const v8s*)wb, b, out, N);
}